// Round 2
// baseline (13662.987 us; speedup 1.0000x reference)
//
#include <hip/hip_runtime.h>
#include <math.h>

#define B_ 16
#define S_ 256
#define T_ 256
#define E_ 1024
#define H_ 512
#define G_ 1536
#define V_ 32000

// ---------------- embedding gathers ----------------
__global__ __launch_bounds__(256) void k_embed_enc(const int* __restrict__ sen,
                                                   const float* __restrict__ emb,
                                                   float* __restrict__ out) {
  long row = blockIdx.x;  // b*S+s
  int tid = threadIdx.x;
  long e = sen[row];
  float4 v = *(const float4*)(emb + e * E_ + tid * 4);
  *(float4*)(out + row * E_ + tid * 4) = v;
}

__global__ __launch_bounds__(256) void k_embed_dec(const int* __restrict__ zh,
                                                   const float* __restrict__ emb,
                                                   float* __restrict__ out) {
  long row = blockIdx.x;  // b*T+t
  int b = (int)(row >> 8), t = (int)(row & 255);
  int tid = threadIdx.x;
  long e = (t == 0) ? (V_ - 2) : zh[b * T_ + t - 1];
  float4 v = *(const float4*)(emb + e * E_ + tid * 4);
  *(float4*)(out + row * E_ + tid * 4) = v;
}

// ---------------- batched 32x32 tiled transpose: in[Z][R][C] -> out[Z][C][R] ----------------
__global__ __launch_bounds__(256) void k_transpose(const float* __restrict__ in,
                                                   float* __restrict__ out, int R, int C) {
  __shared__ float tile[32][33];
  long z = blockIdx.z;
  const float* inz = in + z * (long)R * C;
  float* outz = out + z * (long)R * C;
  int x = blockIdx.x * 32 + threadIdx.x;  // col in input
  int y0 = blockIdx.y * 32;               // row base in input
#pragma unroll
  for (int i = threadIdx.y; i < 32; i += 8)
    tile[i][threadIdx.x] = inz[(long)(y0 + i) * C + x];
  __syncthreads();
  int xo = y0 + threadIdx.x;  // output col = input row
#pragma unroll
  for (int i = threadIdx.y; i < 32; i += 8) {
    int yo = blockIdx.x * 32 + i;  // output row = input col
    outz[(long)yo * R + xo] = tile[threadIdx.x][i];
  }
}

// ---------------- fp32 SGEMM, C[M,N] = A[M,K] * B[N,K]^T (+bias), 128x128x8 tiles ----------------
// Optional concatenated A: columns [0,kSplit) from A (stride lda), [kSplit,K) from A2 (stride lda2).
__global__ __launch_bounds__(256) void k_gemm_nt(
    const float* __restrict__ A, int lda, const float* __restrict__ A2, int lda2, int kSplit,
    const float* __restrict__ Bm, int ldb, const float* __restrict__ bias,
    float* __restrict__ C, int ldc, int K, long sA, long sB, long sC) {
  __shared__ float As[8][132];
  __shared__ float Bs[8][132];
  int z = blockIdx.z;
  A += z * sA;
  Bm += z * sB;
  C += z * sC;
  int tid = threadIdx.x;
  int bm = blockIdx.y * 128, bn = blockIdx.x * 128;
  int tx = tid & 15, ty = tid >> 4;
  int lr = tid >> 1, lc = (tid & 1) * 4;
  float acc[8][8] = {};
  for (int k0 = 0; k0 < K; k0 += 8) {
    int ka = k0 + lc;
    const float* ap;
    if (A2 != nullptr && ka >= kSplit)
      ap = A2 + (long)(bm + lr) * lda2 + (ka - kSplit);
    else
      ap = A + (long)(bm + lr) * lda + ka;
    float4 a4 = *(const float4*)ap;
    float4 b4 = *(const float4*)(Bm + (long)(bn + lr) * ldb + k0 + lc);
    As[lc + 0][lr] = a4.x; As[lc + 1][lr] = a4.y; As[lc + 2][lr] = a4.z; As[lc + 3][lr] = a4.w;
    Bs[lc + 0][lr] = b4.x; Bs[lc + 1][lr] = b4.y; Bs[lc + 2][lr] = b4.z; Bs[lc + 3][lr] = b4.w;
    __syncthreads();
#pragma unroll
    for (int kk = 0; kk < 8; kk++) {
      float ar[8], br[8];
      *(float4*)&ar[0] = *(const float4*)&As[kk][ty * 8];
      *(float4*)&ar[4] = *(const float4*)&As[kk][ty * 8 + 4];
      *(float4*)&br[0] = *(const float4*)&Bs[kk][tx * 8];
      *(float4*)&br[4] = *(const float4*)&Bs[kk][tx * 8 + 4];
#pragma unroll
      for (int i = 0; i < 8; i++)
#pragma unroll
        for (int j = 0; j < 8; j++) acc[i][j] += ar[i] * br[j];
    }
    __syncthreads();
  }
  float bv[8];
#pragma unroll
  for (int j = 0; j < 8; j++) bv[j] = bias ? bias[bn + tx * 8 + j] : 0.f;
#pragma unroll
  for (int i = 0; i < 8; i++) {
    float* cp = C + (long)(bm + ty * 8 + i) * ldc + bn + tx * 8;
    float4 o0, o1;
    o0.x = acc[i][0] + bv[0]; o0.y = acc[i][1] + bv[1];
    o0.z = acc[i][2] + bv[2]; o0.w = acc[i][3] + bv[3];
    o1.x = acc[i][4] + bv[4]; o1.y = acc[i][5] + bv[5];
    o1.z = acc[i][6] + bv[6]; o1.w = acc[i][7] + bv[7];
    *(float4*)cp = o0;
    *(float4*)(cp + 4) = o1;
  }
}

// ---------------- one GRU timestep ----------------
// grid = B*8 blocks (8 j-slices of 64), block = 256 threads (64 j x 4 k-quarters).
// xp: [B][256][1536] precomputed input projection (+bih). y: [B][256][512] outputs (h(t)=y[:,t,:]).
// WhhT: [512][1536]. hinit used at t==0: h(-1)[b][j] = hinit[b*hbs + j].
__global__ __launch_bounds__(256) void k_gru_step(
    const float* __restrict__ xp, float* __restrict__ y,
    const float* __restrict__ WhhT, const float* __restrict__ bhh,
    const float* __restrict__ hinit, long hbs, int t) {
  __shared__ float hs[512];
  __shared__ float red[3][4][64];
  int blk = blockIdx.x;
  int b = blk >> 3, js = blk & 7;
  int tid = threadIdx.x;
  int jj = tid & 63, kq = tid >> 6;
  int j = js * 64 + jj;
  const float* hprev = (t == 0) ? (hinit + (long)b * hbs)
                                : (y + ((long)b * 256 + (t - 1)) * 512);
  hs[tid] = hprev[tid];
  hs[tid + 256] = hprev[tid + 256];
  __syncthreads();
  float a0 = 0.f, a1 = 0.f, a2 = 0.f;
  int k0 = kq * 128;
  const float* wp = WhhT + (long)k0 * 1536;
#pragma unroll 4
  for (int k = 0; k < 128; k++) {
    float hv = hs[k0 + k];
    const float* row = wp + (long)k * 1536;
    a0 += hv * row[j];
    a1 += hv * row[j + 512];
    a2 += hv * row[j + 1024];
  }
  red[0][kq][jj] = a0;
  red[1][kq][jj] = a1;
  red[2][kq][jj] = a2;
  __syncthreads();
  if (kq == 0) {
    float hr = red[0][0][jj] + red[0][1][jj] + red[0][2][jj] + red[0][3][jj] + bhh[j];
    float hz = red[1][0][jj] + red[1][1][jj] + red[1][2][jj] + red[1][3][jj] + bhh[j + 512];
    float hn = red[2][0][jj] + red[2][1][jj] + red[2][2][jj] + red[2][3][jj] + bhh[j + 1024];
    const float* xpt = xp + ((long)b * 256 + t) * 1536;
    float xr = xpt[j], xz = xpt[j + 512], xn = xpt[j + 1024];
    float r = 1.f / (1.f + expf(-(xr + hr)));
    float z = 1.f / (1.f + expf(-(xz + hz)));
    float n = tanhf(xn + r * hn);
    float hp = hs[j];
    y[((long)b * 256 + t) * 512 + j] = (1.f - z) * n + z * hp;
  }
}

// ---------------- row softmax over 256 contiguous elements ----------------
__global__ __launch_bounds__(256) void k_softmax(float* __restrict__ p) {
  long row = blockIdx.x;
  int tid = threadIdx.x;
  float* pr = p + row * 256;
  float v = pr[tid];
  float m = v;
#pragma unroll
  for (int off = 32; off >= 1; off >>= 1) m = fmaxf(m, __shfl_xor(m, off));
  __shared__ float wmax[4];
  __shared__ float wsum[4];
  int wv = tid >> 6, ln = tid & 63;
  if (ln == 0) wmax[wv] = m;
  __syncthreads();
  m = fmaxf(fmaxf(wmax[0], wmax[1]), fmaxf(wmax[2], wmax[3]));
  float e = expf(v - m);
  float s = e;
#pragma unroll
  for (int off = 32; off >= 1; off >>= 1) s += __shfl_xor(s, off);
  if (ln == 0) wsum[wv] = s;
  __syncthreads();
  s = wsum[0] + wsum[1] + wsum[2] + wsum[3];
  pr[tid] = e / s;
}

extern "C" void kernel_launch(void* const* d_in, const int* in_sizes, int n_in,
                              void* d_out, int out_size, void* d_ws, size_t ws_size,
                              hipStream_t stream) {
  const int* en_sen = (const int*)d_in[0];
  const int* zh_sen = (const int*)d_in[1];
  const float* en_emb = (const float*)d_in[2];
  const float* zh_emb = (const float*)d_in[3];
  const float* h0 = (const float*)d_in[4];
  const float* Wih_e0 = (const float*)d_in[5];
  const float* Whh_e0 = (const float*)d_in[6];
  const float* bih_e0 = (const float*)d_in[7];
  const float* bhh_e0 = (const float*)d_in[8];
  const float* Wih_e1 = (const float*)d_in[9];
  const float* Whh_e1 = (const float*)d_in[10];
  const float* bih_e1 = (const float*)d_in[11];
  const float* bhh_e1 = (const float*)d_in[12];
  const float* Wih_d0 = (const float*)d_in[13];
  const float* Whh_d0 = (const float*)d_in[14];
  const float* bih_d0 = (const float*)d_in[15];
  const float* bhh_d0 = (const float*)d_in[16];
  const float* Wih_d1 = (const float*)d_in[17];
  const float* Whh_d1 = (const float*)d_in[18];
  const float* bih_d1 = (const float*)d_in[19];
  const float* bhh_d1 = (const float*)d_in[20];
  const float* fcW = (const float*)d_in[21];
  const float* fcb = (const float*)d_in[22];
  float* out = (float*)d_out;

  // --- FC inputs MUST NOT alias d_out (the FC reads them while overwriting
  // all of d_out from concurrent blocks). Put decOut and ctx in d_ws: 16 MiB.
  float* decOut = (float*)d_ws;     // [B*256*512] y_d1
  float* ctx = decOut + 2097152;    // [B*256*512]

  // Remaining scratch lives in d_out; every region is written before read and
  // fully consumed BEFORE the final FC launch (stream order => no race).
  float* whhT0 = (float*)d_out;
  float* whhT1 = whhT0 + 786432;
  float* whhT2 = whhT1 + 786432;
  float* whhT3 = whhT2 + 786432;
  float* bufE = whhT3 + 786432;    // ex / zx  [B*256*1024]
  float* xp = bufE + 4194304;      // [B*256*1536]
  float* bufY = xp + 6291456;      // y_e0 then y_d0 [B*256*512]
  float* enOut = bufY + 2097152;   // y_e1 [B*256*512]
  float* scT = enOut + 2097152;    // scoresT/attnT [B*256*256]
  float* enOutT = scT + 1048576;   // [B*512*256]

  dim3 tb(32, 8);
  // Pre-transpose recurrent weights: Whh [1536,512] -> WhhT [512,1536]
  k_transpose<<<dim3(16, 48, 1), tb, 0, stream>>>(Whh_e0, whhT0, 1536, 512);
  k_transpose<<<dim3(16, 48, 1), tb, 0, stream>>>(Whh_e1, whhT1, 1536, 512);
  k_transpose<<<dim3(16, 48, 1), tb, 0, stream>>>(Whh_d0, whhT2, 1536, 512);
  k_transpose<<<dim3(16, 48, 1), tb, 0, stream>>>(Whh_d1, whhT3, 1536, 512);

  // ---------------- encoder ----------------
  k_embed_enc<<<B_ * S_, 256, 0, stream>>>(en_sen, en_emb, bufE);
  k_gemm_nt<<<dim3(G_ / 128, (B_ * S_) / 128, 1), 256, 0, stream>>>(
      bufE, E_, nullptr, 0, E_, Wih_e0, E_, bih_e0, xp, G_, E_, 0, 0, 0);
  for (int t = 0; t < S_; t++)
    k_gru_step<<<B_ * 8, 256, 0, stream>>>(xp, bufY, whhT0, bhh_e0, h0, (long)H_, t);
  k_gemm_nt<<<dim3(G_ / 128, (B_ * S_) / 128, 1), 256, 0, stream>>>(
      bufY, H_, nullptr, 0, H_, Wih_e1, H_, bih_e1, xp, G_, H_, 0, 0, 0);
  for (int t = 0; t < S_; t++)
    k_gru_step<<<B_ * 8, 256, 0, stream>>>(xp, enOut, whhT1, bhh_e1, h0 + B_ * H_, (long)H_, t);

  // ---------------- decoder ----------------
  k_embed_dec<<<B_ * T_, 256, 0, stream>>>(zh_sen, zh_emb, bufE);
  k_gemm_nt<<<dim3(G_ / 128, (B_ * T_) / 128, 1), 256, 0, stream>>>(
      bufE, E_, nullptr, 0, E_, Wih_d0, E_, bih_d0, xp, G_, E_, 0, 0, 0);
  for (int t = 0; t < T_; t++)  // init h = y_e0[:,255,:] (still in bufY; row 255 read only at t=0)
    k_gru_step<<<B_ * 8, 256, 0, stream>>>(xp, bufY, whhT2, bhh_d0, bufY + 255 * H_,
                                           (long)(256 * H_), t);
  k_gemm_nt<<<dim3(G_ / 128, (B_ * T_) / 128, 1), 256, 0, stream>>>(
      bufY, H_, nullptr, 0, H_, Wih_d1, H_, bih_d1, xp, G_, H_, 0, 0, 0);
  for (int t = 0; t < T_; t++)
    k_gru_step<<<B_ * 8, 256, 0, stream>>>(xp, decOut, whhT3, bhh_d1, enOut + 255 * H_,
                                           (long)(256 * H_), t);

  // ---------------- attention ----------------
  // scoresT[b,t,s] = sum_h decOut[b,t,h] * enOut[b,s,h]
  k_gemm_nt<<<dim3(S_ / 128, T_ / 128, B_), 256, 0, stream>>>(
      decOut, H_, nullptr, 0, H_, enOut, H_, nullptr, scT, S_, H_,
      (long)T_ * H_, (long)S_ * H_, (long)T_ * S_);
  k_softmax<<<B_ * T_, 256, 0, stream>>>(scT);
  // enOutT[b,h,s]
  k_transpose<<<dim3(16, 8, B_), tb, 0, stream>>>(enOut, enOutT, 256, 512);
  // ctx[b,t,h] = sum_s attnT[b,t,s] * enOutT[b,h,s]
  k_gemm_nt<<<dim3(H_ / 128, T_ / 128, B_), 256, 0, stream>>>(
      scT, S_, nullptr, 0, S_, enOutT, S_, nullptr, ctx, H_, S_,
      (long)T_ * S_, (long)H_ * S_, (long)T_ * H_);

  // ---------------- final FC: out = [decOut|ctx] @ fcW^T + fcb ----------------
  // Reads only d_ws (decOut, ctx) + inputs; writes all of d_out. No aliasing.
  k_gemm_nt<<<dim3(V_ / 128, (B_ * T_) / 128, 1), 256, 0, stream>>>(
      decOut, H_, ctx, H_, H_, fcW, E_, fcb, out, V_, E_, 0, 0, 0);
}

// Round 3
// 10315.667 us; speedup vs baseline: 1.3245x; 1.3245x over previous
//
#include <hip/hip_runtime.h>
#include <math.h>

#define B_ 16
#define S_ 256
#define T_ 256
#define E_ 1024
#define H_ 512
#define G_ 1536
#define V_ 32000

typedef unsigned short u16;
typedef short short8 __attribute__((ext_vector_type(8)));
typedef float f32x4 __attribute__((ext_vector_type(4)));

// float -> bf16 (RNE, finite inputs) and back
__device__ inline u16 f2bf(float x) {
  union { float f; unsigned u; } a; a.f = x;
  unsigned r = a.u + 0x7fff + ((a.u >> 16) & 1);
  return (u16)(r >> 16);
}
__device__ inline float bf2f(u16 h) {
  union { unsigned u; float f; } a; a.u = ((unsigned)h) << 16;
  return a.f;
}

// ---------------- embedding gathers ----------------
__global__ __launch_bounds__(256) void k_embed_enc(const int* __restrict__ sen,
                                                   const float* __restrict__ emb,
                                                   float* __restrict__ out) {
  long row = blockIdx.x;  // b*S+s
  int tid = threadIdx.x;
  long e = sen[row];
  float4 v = *(const float4*)(emb + e * E_ + tid * 4);
  *(float4*)(out + row * E_ + tid * 4) = v;
}

__global__ __launch_bounds__(256) void k_embed_dec(const int* __restrict__ zh,
                                                   const float* __restrict__ emb,
                                                   float* __restrict__ out) {
  long row = blockIdx.x;  // b*T+t
  int b = (int)(row >> 8), t = (int)(row & 255);
  int tid = threadIdx.x;
  long e = (t == 0) ? (V_ - 2) : zh[b * T_ + t - 1];
  float4 v = *(const float4*)(emb + e * E_ + tid * 4);
  *(float4*)(out + row * E_ + tid * 4) = v;
}

// ---------------- batched 32x32 tiled transpose: in[Z][R][C] -> out[Z][C][R] ----------------
__global__ __launch_bounds__(256) void k_transpose(const float* __restrict__ in,
                                                   float* __restrict__ out, int R, int C) {
  __shared__ float tile[32][33];
  long z = blockIdx.z;
  const float* inz = in + z * (long)R * C;
  float* outz = out + z * (long)R * C;
  int x = blockIdx.x * 32 + threadIdx.x;
  int y0 = blockIdx.y * 32;
#pragma unroll
  for (int i = threadIdx.y; i < 32; i += 8)
    tile[i][threadIdx.x] = inz[(long)(y0 + i) * C + x];
  __syncthreads();
  int xo = y0 + threadIdx.x;
#pragma unroll
  for (int i = threadIdx.y; i < 32; i += 8) {
    int yo = blockIdx.x * 32 + i;
    outz[(long)yo * R + xo] = tile[threadIdx.x][i];
  }
}

// ---------------- fp32 SGEMM (kept for small attention GEMMs) ----------------
__global__ __launch_bounds__(256) void k_gemm_nt(
    const float* __restrict__ A, int lda, const float* __restrict__ A2, int lda2, int kSplit,
    const float* __restrict__ Bm, int ldb, const float* __restrict__ bias,
    float* __restrict__ C, int ldc, int K, long sA, long sB, long sC) {
  __shared__ float As[8][132];
  __shared__ float Bs[8][132];
  int z = blockIdx.z;
  A += z * sA;
  Bm += z * sB;
  C += z * sC;
  int tid = threadIdx.x;
  int bm = blockIdx.y * 128, bn = blockIdx.x * 128;
  int tx = tid & 15, ty = tid >> 4;
  int lr = tid >> 1, lc = (tid & 1) * 4;
  float acc[8][8] = {};
  for (int k0 = 0; k0 < K; k0 += 8) {
    int ka = k0 + lc;
    const float* ap;
    if (A2 != nullptr && ka >= kSplit)
      ap = A2 + (long)(bm + lr) * lda2 + (ka - kSplit);
    else
      ap = A + (long)(bm + lr) * lda + ka;
    float4 a4 = *(const float4*)ap;
    float4 b4 = *(const float4*)(Bm + (long)(bn + lr) * ldb + k0 + lc);
    As[lc + 0][lr] = a4.x; As[lc + 1][lr] = a4.y; As[lc + 2][lr] = a4.z; As[lc + 3][lr] = a4.w;
    Bs[lc + 0][lr] = b4.x; Bs[lc + 1][lr] = b4.y; Bs[lc + 2][lr] = b4.z; Bs[lc + 3][lr] = b4.w;
    __syncthreads();
#pragma unroll
    for (int kk = 0; kk < 8; kk++) {
      float ar[8], br[8];
      *(float4*)&ar[0] = *(const float4*)&As[kk][ty * 8];
      *(float4*)&ar[4] = *(const float4*)&As[kk][ty * 8 + 4];
      *(float4*)&br[0] = *(const float4*)&Bs[kk][tx * 8];
      *(float4*)&br[4] = *(const float4*)&Bs[kk][tx * 8 + 4];
#pragma unroll
      for (int i = 0; i < 8; i++)
#pragma unroll
        for (int j = 0; j < 8; j++) acc[i][j] += ar[i] * br[j];
    }
    __syncthreads();
  }
  float bv[8];
#pragma unroll
  for (int j = 0; j < 8; j++) bv[j] = bias ? bias[bn + tx * 8 + j] : 0.f;
#pragma unroll
  for (int i = 0; i < 8; i++) {
    float* cp = C + (long)(bm + ty * 8 + i) * ldc + bn + tx * 8;
    float4 o0, o1;
    o0.x = acc[i][0] + bv[0]; o0.y = acc[i][1] + bv[1];
    o0.z = acc[i][2] + bv[2]; o0.w = acc[i][3] + bv[3];
    o1.x = acc[i][4] + bv[4]; o1.y = acc[i][5] + bv[5];
    o1.z = acc[i][6] + bv[6]; o1.w = acc[i][7] + bv[7];
    *(float4*)cp = o0;
    *(float4*)(cp + 4) = o1;
  }
}

// ---------------- split-bf16 MFMA GEMM: C[M,N] = A[M,K]*B[N,K]^T + bias ----------------
// fp32 in/out; internally A,B are staged to LDS as (hi,lo) bf16 pairs and the
// product uses 3 MFMAs (hi*hi + hi*lo + lo*hi) per k-tile -> fp32-class accuracy.
// 128x128 tile, BK=32, 256 threads = 4 waves (2x2), each wave 64x64 out.
// Optional concat A: cols [0,kSplit) from A, [kSplit,K) from A2 (kSplit % 16 == 0).
#define BKP 40  // LDS col stride (bf16) -> 80B row stride, ~2-way conflicts
__global__ __launch_bounds__(256) void k_gemm_mfma_nt(
    const float* __restrict__ A, int lda, const float* __restrict__ A2, int lda2, int kSplit,
    const float* __restrict__ Bm, int ldb, const float* __restrict__ bias,
    float* __restrict__ C, int ldc, int K) {
  __shared__ u16 Ah[128][BKP];
  __shared__ u16 Al[128][BKP];
  __shared__ u16 Bh[128][BKP];
  __shared__ u16 Bl[128][BKP];
  int tid = threadIdx.x;
  int bm = blockIdx.y * 128, bn = blockIdx.x * 128;
  int wave = tid >> 6, lane = tid & 63;
  int wm = (wave >> 1) * 64, wn = (wave & 1) * 64;
  int srow = tid >> 1, scol = (tid & 1) * 16;  // staging: 16 k-elems per thread per tile
  int fr = lane & 15, fk = (lane >> 4) * 8, fq = lane >> 4;

  f32x4 acc[4][4] = {};

  for (int k0 = 0; k0 < K; k0 += 32) {
    // ---- stage A tile (fp32 -> hi/lo bf16) ----
    {
      int ka = k0 + scol;
      const float* ap;
      if (A2 != nullptr && ka >= kSplit)
        ap = A2 + (long)(bm + srow) * lda2 + (ka - kSplit);
      else
        ap = A + (long)(bm + srow) * lda + ka;
      float va[16];
      *(float4*)&va[0] = *(const float4*)ap;
      *(float4*)&va[4] = *(const float4*)(ap + 4);
      *(float4*)&va[8] = *(const float4*)(ap + 8);
      *(float4*)&va[12] = *(const float4*)(ap + 12);
      u16 h[16], l[16];
#pragma unroll
      for (int i = 0; i < 16; i++) {
        u16 hh = f2bf(va[i]);
        h[i] = hh;
        l[i] = f2bf(va[i] - bf2f(hh));
      }
      *(short8*)&Ah[srow][scol] = *(short8*)&h[0];
      *(short8*)&Ah[srow][scol + 8] = *(short8*)&h[8];
      *(short8*)&Al[srow][scol] = *(short8*)&l[0];
      *(short8*)&Al[srow][scol + 8] = *(short8*)&l[8];
    }
    // ---- stage B tile ----
    {
      const float* bp = Bm + (long)(bn + srow) * ldb + k0 + scol;
      float vb[16];
      *(float4*)&vb[0] = *(const float4*)bp;
      *(float4*)&vb[4] = *(const float4*)(bp + 4);
      *(float4*)&vb[8] = *(const float4*)(bp + 8);
      *(float4*)&vb[12] = *(const float4*)(bp + 12);
      u16 h[16], l[16];
#pragma unroll
      for (int i = 0; i < 16; i++) {
        u16 hh = f2bf(vb[i]);
        h[i] = hh;
        l[i] = f2bf(vb[i] - bf2f(hh));
      }
      *(short8*)&Bh[srow][scol] = *(short8*)&h[0];
      *(short8*)&Bh[srow][scol + 8] = *(short8*)&h[8];
      *(short8*)&Bl[srow][scol] = *(short8*)&l[0];
      *(short8*)&Bl[srow][scol + 8] = *(short8*)&l[8];
    }
    __syncthreads();
    // ---- MFMA: 3 products per (mt,nt) ----
    short8 afh[4], afl[4];
#pragma unroll
    for (int mt = 0; mt < 4; mt++) {
      afh[mt] = *(const short8*)&Ah[wm + mt * 16 + fr][fk];
      afl[mt] = *(const short8*)&Al[wm + mt * 16 + fr][fk];
    }
#pragma unroll
    for (int nt = 0; nt < 4; nt++) {
      short8 bh = *(const short8*)&Bh[wn + nt * 16 + fr][fk];
      short8 bl = *(const short8*)&Bl[wn + nt * 16 + fr][fk];
#pragma unroll
      for (int mt = 0; mt < 4; mt++) {
        acc[mt][nt] = __builtin_amdgcn_mfma_f32_16x16x32_bf16(afh[mt], bh, acc[mt][nt], 0, 0, 0);
        acc[mt][nt] = __builtin_amdgcn_mfma_f32_16x16x32_bf16(afh[mt], bl, acc[mt][nt], 0, 0, 0);
        acc[mt][nt] = __builtin_amdgcn_mfma_f32_16x16x32_bf16(afl[mt], bh, acc[mt][nt], 0, 0, 0);
      }
    }
    __syncthreads();
  }
  // ---- epilogue: C/D layout col=lane&15, row=(lane>>4)*4+j (m89-verified) ----
#pragma unroll
  for (int nt = 0; nt < 4; nt++) {
    int col = bn + wn + nt * 16 + fr;
    float bv = bias ? bias[col] : 0.f;
#pragma unroll
    for (int mt = 0; mt < 4; mt++) {
      int row = bm + wm + mt * 16 + fq * 4;
#pragma unroll
      for (int j = 0; j < 4; j++)
        C[(long)(row + j) * ldc + col] = acc[mt][nt][j] + bv;
    }
  }
}

// ---------------- one GRU timestep ----------------
__global__ __launch_bounds__(256) void k_gru_step(
    const float* __restrict__ xp, float* __restrict__ y,
    const float* __restrict__ WhhT, const float* __restrict__ bhh,
    const float* __restrict__ hinit, long hbs, int t) {
  __shared__ float hs[512];
  __shared__ float red[3][4][64];
  int blk = blockIdx.x;
  int b = blk >> 3, js = blk & 7;
  int tid = threadIdx.x;
  int jj = tid & 63, kq = tid >> 6;
  int j = js * 64 + jj;
  const float* hprev = (t == 0) ? (hinit + (long)b * hbs)
                                : (y + ((long)b * 256 + (t - 1)) * 512);
  hs[tid] = hprev[tid];
  hs[tid + 256] = hprev[tid + 256];
  __syncthreads();
  float a0 = 0.f, a1 = 0.f, a2 = 0.f;
  int k0 = kq * 128;
  const float* wp = WhhT + (long)k0 * 1536;
#pragma unroll 4
  for (int k = 0; k < 128; k++) {
    float hv = hs[k0 + k];
    const float* row = wp + (long)k * 1536;
    a0 += hv * row[j];
    a1 += hv * row[j + 512];
    a2 += hv * row[j + 1024];
  }
  red[0][kq][jj] = a0;
  red[1][kq][jj] = a1;
  red[2][kq][jj] = a2;
  __syncthreads();
  if (kq == 0) {
    float hr = red[0][0][jj] + red[0][1][jj] + red[0][2][jj] + red[0][3][jj] + bhh[j];
    float hz = red[1][0][jj] + red[1][1][jj] + red[1][2][jj] + red[1][3][jj] + bhh[j + 512];
    float hn = red[2][0][jj] + red[2][1][jj] + red[2][2][jj] + red[2][3][jj] + bhh[j + 1024];
    const float* xpt = xp + ((long)b * 256 + t) * 1536;
    float xr = xpt[j], xz = xpt[j + 512], xn = xpt[j + 1024];
    float r = 1.f / (1.f + expf(-(xr + hr)));
    float z = 1.f / (1.f + expf(-(xz + hz)));
    float n = tanhf(xn + r * hn);
    float hp = hs[j];
    y[((long)b * 256 + t) * 512 + j] = (1.f - z) * n + z * hp;
  }
}

// ---------------- row softmax over 256 contiguous elements ----------------
__global__ __launch_bounds__(256) void k_softmax(float* __restrict__ p) {
  long row = blockIdx.x;
  int tid = threadIdx.x;
  float* pr = p + row * 256;
  float v = pr[tid];
  float m = v;
#pragma unroll
  for (int off = 32; off >= 1; off >>= 1) m = fmaxf(m, __shfl_xor(m, off));
  __shared__ float wmax[4];
  __shared__ float wsum[4];
  int wv = tid >> 6, ln = tid & 63;
  if (ln == 0) wmax[wv] = m;
  __syncthreads();
  m = fmaxf(fmaxf(wmax[0], wmax[1]), fmaxf(wmax[2], wmax[3]));
  float e = expf(v - m);
  float s = e;
#pragma unroll
  for (int off = 32; off >= 1; off >>= 1) s += __shfl_xor(s, off);
  if (ln == 0) wsum[wv] = s;
  __syncthreads();
  s = wsum[0] + wsum[1] + wsum[2] + wsum[3];
  pr[tid] = e / s;
}

extern "C" void kernel_launch(void* const* d_in, const int* in_sizes, int n_in,
                              void* d_out, int out_size, void* d_ws, size_t ws_size,
                              hipStream_t stream) {
  const int* en_sen = (const int*)d_in[0];
  const int* zh_sen = (const int*)d_in[1];
  const float* en_emb = (const float*)d_in[2];
  const float* zh_emb = (const float*)d_in[3];
  const float* h0 = (const float*)d_in[4];
  const float* Wih_e0 = (const float*)d_in[5];
  const float* Whh_e0 = (const float*)d_in[6];
  const float* bih_e0 = (const float*)d_in[7];
  const float* bhh_e0 = (const float*)d_in[8];
  const float* Wih_e1 = (const float*)d_in[9];
  const float* Whh_e1 = (const float*)d_in[10];
  const float* bih_e1 = (const float*)d_in[11];
  const float* bhh_e1 = (const float*)d_in[12];
  const float* Wih_d0 = (const float*)d_in[13];
  const float* Whh_d0 = (const float*)d_in[14];
  const float* bih_d0 = (const float*)d_in[15];
  const float* bhh_d0 = (const float*)d_in[16];
  const float* Wih_d1 = (const float*)d_in[17];
  const float* Whh_d1 = (const float*)d_in[18];
  const float* bih_d1 = (const float*)d_in[19];
  const float* bhh_d1 = (const float*)d_in[20];
  const float* fcW = (const float*)d_in[21];
  const float* fcb = (const float*)d_in[22];
  float* out = (float*)d_out;

  // FC inputs must not alias d_out (FC writes all of d_out) -> d_ws (16 MiB).
  float* decOut = (float*)d_ws;     // [B*256*512] y_d1
  float* ctx = decOut + 2097152;    // [B*256*512]

  // Remaining scratch in d_out; written-before-read, fully consumed before FC.
  float* whhT0 = (float*)d_out;
  float* whhT1 = whhT0 + 786432;
  float* whhT2 = whhT1 + 786432;
  float* whhT3 = whhT2 + 786432;
  float* bufE = whhT3 + 786432;    // ex / zx  [B*256*1024]
  float* xp = bufE + 4194304;      // [B*256*1536]
  float* bufY = xp + 6291456;      // y_e0 then y_d0 [B*256*512]
  float* enOut = bufY + 2097152;   // y_e1 [B*256*512]
  float* scT = enOut + 2097152;    // scoresT/attnT [B*256*256]
  float* enOutT = scT + 1048576;   // [B*512*256]

  dim3 tb(32, 8);
  k_transpose<<<dim3(16, 48, 1), tb, 0, stream>>>(Whh_e0, whhT0, 1536, 512);
  k_transpose<<<dim3(16, 48, 1), tb, 0, stream>>>(Whh_e1, whhT1, 1536, 512);
  k_transpose<<<dim3(16, 48, 1), tb, 0, stream>>>(Whh_d0, whhT2, 1536, 512);
  k_transpose<<<dim3(16, 48, 1), tb, 0, stream>>>(Whh_d1, whhT3, 1536, 512);

  // ---------------- encoder ----------------
  k_embed_enc<<<B_ * S_, 256, 0, stream>>>(en_sen, en_emb, bufE);
  k_gemm_mfma_nt<<<dim3(G_ / 128, (B_ * S_) / 128, 1), 256, 0, stream>>>(
      bufE, E_, nullptr, 0, E_, Wih_e0, E_, bih_e0, xp, G_, E_);
  for (int t = 0; t < S_; t++)
    k_gru_step<<<B_ * 8, 256, 0, stream>>>(xp, bufY, whhT0, bhh_e0, h0, (long)H_, t);
  k_gemm_mfma_nt<<<dim3(G_ / 128, (B_ * S_) / 128, 1), 256, 0, stream>>>(
      bufY, H_, nullptr, 0, H_, Wih_e1, H_, bih_e1, xp, G_, H_);
  for (int t = 0; t < S_; t++)
    k_gru_step<<<B_ * 8, 256, 0, stream>>>(xp, enOut, whhT1, bhh_e1, h0 + B_ * H_, (long)H_, t);

  // ---------------- decoder ----------------
  k_embed_dec<<<B_ * T_, 256, 0, stream>>>(zh_sen, zh_emb, bufE);
  k_gemm_mfma_nt<<<dim3(G_ / 128, (B_ * T_) / 128, 1), 256, 0, stream>>>(
      bufE, E_, nullptr, 0, E_, Wih_d0, E_, bih_d0, xp, G_, E_);
  for (int t = 0; t < T_; t++)  // init h = y_e0[:,255,:] (bufY row 255 read only at t=0)
    k_gru_step<<<B_ * 8, 256, 0, stream>>>(xp, bufY, whhT2, bhh_d0, bufY + 255 * H_,
                                           (long)(256 * H_), t);
  k_gemm_mfma_nt<<<dim3(G_ / 128, (B_ * T_) / 128, 1), 256, 0, stream>>>(
      bufY, H_, nullptr, 0, H_, Wih_d1, H_, bih_d1, xp, G_, H_);
  for (int t = 0; t < T_; t++)
    k_gru_step<<<B_ * 8, 256, 0, stream>>>(xp, decOut, whhT3, bhh_d1, enOut + 255 * H_,
                                           (long)(256 * H_), t);

  // ---------------- attention (fp32, small) ----------------
  k_gemm_nt<<<dim3(S_ / 128, T_ / 128, B_), 256, 0, stream>>>(
      decOut, H_, nullptr, 0, H_, enOut, H_, nullptr, scT, S_, H_,
      (long)T_ * H_, (long)S_ * H_, (long)T_ * S_);
  k_softmax<<<B_ * T_, 256, 0, stream>>>(scT);
  k_transpose<<<dim3(16, 8, B_), tb, 0, stream>>>(enOut, enOutT, 256, 512);
  k_gemm_nt<<<dim3(H_ / 128, T_ / 128, B_), 256, 0, stream>>>(
      scT, S_, nullptr, 0, S_, enOutT, S_, nullptr, ctx, H_, S_,
      (long)T_ * S_, (long)H_ * S_, (long)T_ * H_);

  // ---------------- final FC: out = [decOut|ctx] @ fcW^T + fcb (split-bf16 MFMA) ----------------
  k_gemm_mfma_nt<<<dim3(V_ / 128, (B_ * T_) / 128, 1), 256, 0, stream>>>(
      decOut, H_, ctx, H_, H_, fcW, E_, fcb, out, V_, E_);
}